// Round 5
// baseline (255.569 us; speedup 1.0000x reference)
//
#include <hip/hip_runtime.h>
#include <hip/hip_fp16.h>

#define N_NODES 50000
#define N_EDGES 800000
#define F_INN   128
#define F_HID   96
#define F_OUTT  40

typedef _Float16 half8 __attribute__((ext_vector_type(8)));
typedef float    floatx4 __attribute__((ext_vector_type(4)));

// ---------------------------------------------------------------------------
// MFMA GEMM body: T[n][96] (fp16, UNSCALED) = X[n x FI] @ W, via 16x16x32 f16.
// A = W^T tile (m=feature), B = node rows (n=node). 4 waves x 16 nodes = 64/blk.
// TIN = float (load+cvt) or __half (direct half8 load).
// LDS: single 26112B buffer; BT tile while computing, then (after a barrier)
// reused as the 13312B OUT staging area -> 6 blocks/CU instead of 4.
// ---------------------------------------------------------------------------
template <int FI, typename TIN>
__device__ __forceinline__ void mfma_gemm_body(
        const TIN* __restrict__ X, const __half* __restrict__ BTg,
        float4* __restrict__ Th4, int n, int bx) {
    __shared__ __half BTl[96 * 136];          // 26112 B; reused as OUT staging
    __half* OUTl = BTl;                       // [4*16][104] after the barrier
    int tid = threadIdx.x;
    {   // stage BT (1632 x 16B)
        const int4* s = reinterpret_cast<const int4*>(BTg);
        int4* d = reinterpret_cast<int4*>(BTl);
        for (int i = tid; i < 96 * 136 / 8; i += 256) d[i] = s[i];
    }
    __syncthreads();

    int lane = tid & 63, w = tid >> 6;
    int lm = lane & 15, q = lane >> 4;
    int base = bx * 64 + w * 16;
    int node = base + lm;
    int nclamp = min(node, n - 1);
    const TIN* Xrow = X + (size_t)nclamp * FI;

    floatx4 cf[6];
    #pragma unroll
    for (int t = 0; t < 6; ++t) cf[t] = (floatx4){0.f, 0.f, 0.f, 0.f};

    constexpr int KS = FI / 32;
    #pragma unroll
    for (int ks = 0; ks < KS; ++ks) {
        // B-operand: lane holds k = 32*ks + q*8 .. +7 of this node's row
        half8 bv;
        if constexpr (sizeof(TIN) == 4) {
            const float4* xr = reinterpret_cast<const float4*>(Xrow + 32 * ks + q * 8);
            float4 f0 = xr[0], f1 = xr[1];
            union { half8 v; __half2 h[4]; } b;
            b.h[0] = __floats2half2_rn(f0.x, f0.y);
            b.h[1] = __floats2half2_rn(f0.z, f0.w);
            b.h[2] = __floats2half2_rn(f1.x, f1.y);
            b.h[3] = __floats2half2_rn(f1.z, f1.w);
            bv = b.v;
        } else {
            bv = *reinterpret_cast<const half8*>(Xrow + 32 * ks + q * 8);
        }
        #pragma unroll
        for (int t = 0; t < 6; ++t) {
            half8 a = *reinterpret_cast<const half8*>(
                &BTl[(t * 16 + lm) * 136 + q * 8 + 32 * ks]);
            cf[t] = __builtin_amdgcn_mfma_f32_16x16x32_f16(a, bv, cf[t], 0, 0, 0);
        }
    }

    __syncthreads();   // all waves done reading BTl; safe to reuse as OUTl

    // Epilogue: D[row=q*4+r][col=lm] = out[feature = t*16+q*4+r][node=lm].
    __half* orow = OUTl + (w * 16 + lm) * 104;
    #pragma unroll
    for (int t = 0; t < 6; ++t) {
        union { int2 i2; __half2 h[2]; } u;
        u.h[0] = __floats2half2_rn(cf[t][0], cf[t][1]);
        u.h[1] = __floats2half2_rn(cf[t][2], cf[t][3]);
        *reinterpret_cast<int2*>(&orow[t * 16 + q * 4]) = u.i2;
    }
    // Same-wave LDS round-trip: coalesced fp16 row store (12 x float4 per node).
    #pragma unroll
    for (int R = 0; R < 3; ++R) {
        int nl = lane >> 2, c = (lane & 3) + 4 * R;
        float4 v = *reinterpret_cast<const float4*>(&OUTl[(w * 16 + nl) * 104 + c * 8]);
        int gn = base + nl;
        if (gn < n) Th4[(size_t)gn * 12 + c] = v;
    }
}

// ---------------------------------------------------------------------------
// Fused: count (blocks [0,nCB)) + gemm L1 (blocks [nCB, nCB+GB)) — independent.
// Count phase: FIRE-AND-FORGET atomics (result unused -> no-return
// global_atomic_add, no round-trip wait). Rank is gone; the single returning
// atomic per edge now lives in fill_csr.
// ---------------------------------------------------------------------------
__global__ __launch_bounds__(256) void count_gemm1_kernel(
        const int* __restrict__ dst, int* __restrict__ counts4,
        int e, const float* __restrict__ X, const __half* __restrict__ BT1,
        float4* __restrict__ Th4, int n, int nCB) {
    if ((int)blockIdx.x < nCB) {
        int i = blockIdx.x * 512 + threadIdx.x;
        int j = i + 256;
        int di = 0, dj = 0;
        bool bi = i < e, bj = j < e;
        if (bi) di = dst[i];
        if (bj) dj = dst[j];
        if (bi) atomicAdd(&counts4[di * 4 + (i & 3)], 1);
        if (bj) atomicAdd(&counts4[dj * 4 + (j & 3)], 1);
    } else {
        mfma_gemm_body<F_INN, float>(X, BT1, Th4, n, blockIdx.x - nCB);
    }
}

template <int FI, typename TIN>
__global__ __launch_bounds__(256) void mfma_gemm_kernel(
        const TIN* __restrict__ X, const __half* __restrict__ BTg,
        float4* __restrict__ Th4, int n) {
    mfma_gemm_body<FI, TIN>(X, BTg, Th4, n, blockIdx.x);
}

// ---------------------------------------------------------------------------
// Weight transpose + fp16: W[K x 96] -> BT[96][136] (pad 8). W1 & W2 together.
// ---------------------------------------------------------------------------
__global__ void wt_kernel(const float* __restrict__ W1, const float* __restrict__ W2,
                          __half* __restrict__ BT1, __half* __restrict__ BT2) {
    int i = blockIdx.x * 256 + threadIdx.x;
    if (i < 96 * 128) {
        int j = i / 128, k = i - j * 128;
        BT1[j * 136 + k] = __float2half(W1[k * 96 + j]);
    } else if (i < 96 * 128 + 96 * 96) {
        int t = i - 96 * 128;
        int j = t / 96, k = t - j * 96;
        BT2[j * 136 + k] = __float2half(W2[k * 96 + j]);
    }
}

// ---------------------------------------------------------------------------
// Scan phase 1: per-block exclusive scan of node degrees; dinv; block sums.
// ---------------------------------------------------------------------------
__global__ __launch_bounds__(1024) void scan_local_kernel(
        const int4* __restrict__ counts4, int* __restrict__ row_start,
        float* __restrict__ dinv, int* __restrict__ blk_sums, int n) {
    __shared__ int wave_sums[16];
    int tid = threadIdx.x, lane = tid & 63, wid = tid >> 6;
    int i = blockIdx.x * 1024 + tid;
    int v = 0;
    if (i < n) {
        int4 c = counts4[i];
        v = c.x + c.y + c.z + c.w;
    }
    int val = v;
    #pragma unroll
    for (int off = 1; off < 64; off <<= 1) {
        int u = __shfl_up(val, off, 64);
        if (lane >= off) val += u;
    }
    if (lane == 63) wave_sums[wid] = val;
    __syncthreads();
    if (wid == 0) {
        int w = (lane < 16) ? wave_sums[lane] : 0;
        #pragma unroll
        for (int off = 1; off < 16; off <<= 1) {
            int u = __shfl_up(w, off, 64);
            if (lane >= off) w += u;
        }
        if (lane < 16) wave_sums[lane] = w;
    }
    __syncthreads();
    int excl = ((wid == 0) ? 0 : wave_sums[wid - 1]) + (val - v);
    if (i < n) {
        row_start[i] = excl;                  // local; global offset in phase 2
        dinv[i] = rsqrtf((float)(v + 1));     // +1 self loop
    }
    if (tid == 0) blk_sums[blockIdx.x] = wave_sums[15];
}

// ---------------------------------------------------------------------------
// Scan phase 2+3 fused: every block redundantly scans the <=64 block sums,
// applies its own offset, emits per-shard CURSORS cursor4 (mutated by fill).
// Block 0 writes total.
// ---------------------------------------------------------------------------
__global__ __launch_bounds__(1024) void scan_apply_kernel(
        int* __restrict__ row_start, const int* __restrict__ blk_sums,
        const int4* __restrict__ counts4, int4* __restrict__ cursor4, int n, int nblk) {
    __shared__ int s_my, s_tot;
    int tid = threadIdx.x;
    if (tid < 64) {
        int v = (tid < nblk) ? blk_sums[tid] : 0;
        int val = v;
        #pragma unroll
        for (int off = 1; off < 64; off <<= 1) {
            int u = __shfl_up(val, off, 64);
            if (tid >= off) val += u;
        }
        if (tid == (int)blockIdx.x) s_my = val - v;   // exclusive prefix
        if (tid == 63) s_tot = val;                   // grand total == E
    }
    __syncthreads();
    int i = blockIdx.x * 1024 + tid;
    if (i < n) {
        int4 c = counts4[i];
        int b = row_start[i] + s_my;
        row_start[i] = b;
        cursor4[i] = make_int4(b, b + c.x, b + c.x + c.y, b + c.x + c.y + c.z);
    }
    if (blockIdx.x == 0 && tid == 0) row_start[n] = s_tot;
}

// ---------------------------------------------------------------------------
// Fill: pos = atomicAdd(cursor[dst].shard, 1) — the ONE returning atomic per
// edge.  4 edges/thread keeps 4 round-trips in flight.  Shard id (i&3) is
// identical to the count pass (stride 256 == 0 mod 4).
// ---------------------------------------------------------------------------
__global__ __launch_bounds__(256) void fill_csr_kernel(
        const int* __restrict__ src, const int* __restrict__ dst,
        int* __restrict__ cursor4, int* __restrict__ csr_src, int e) {
    int i0 = blockIdx.x * 1024 + threadIdx.x;
    int sh = i0 & 3;
    int d[4], s[4], p[4];
    bool b[4];
    #pragma unroll
    for (int u = 0; u < 4; ++u) {
        int i = i0 + u * 256;
        b[u] = i < e;
        if (b[u]) { d[u] = dst[i]; s[u] = src[i]; }
    }
    #pragma unroll
    for (int u = 0; u < 4; ++u)
        if (b[u]) p[u] = atomicAdd(&cursor4[d[u] * 4 + sh], 1);
    #pragma unroll
    for (int u = 0; u < 4; ++u)
        if (b[u]) csr_src[p[u]] = s[u];
}

// ---------------------------------------------------------------------------
// Aggregation: one wave per node; T unscaled fp16; per-edge weight dinv[s] is
// a wave-uniform SCALAR load.  H[d] = relu(dinv[d]*(Σ dinv[s]T[s] + dinv[d]T[d]) + b)
// Output fp16.
// ---------------------------------------------------------------------------
__global__ __launch_bounds__(256) void agg_kernel(
        const __half2* __restrict__ T, const int* __restrict__ row_start,
        const int* __restrict__ csr_src, const float* __restrict__ dinv,
        const float* __restrict__ bias, __half2* __restrict__ H, int n) {
    int lane = threadIdx.x & 63;
    int node = __builtin_amdgcn_readfirstlane(blockIdx.x * 4 + (threadIdx.x >> 6));
    if (node >= n) return;
    int fl = min(lane, 47);                    // lanes 48..63 duplicate lane 47

    float dn = dinv[node];
    float2 self = __half22float2(T[(size_t)node * 48 + fl]);
    float accx = dn * self.x, accy = dn * self.y;   // dinv[d]*T[d]

    int idx = row_start[node];
    int end = row_start[node + 1];
    for (; idx + 8 <= end; idx += 8) {
        int s[8];
        #pragma unroll
        for (int u = 0; u < 8; ++u) s[u] = csr_src[idx + u];
        float ws[8];
        #pragma unroll
        for (int u = 0; u < 8; ++u) ws[u] = dinv[s[u]];          // scalar loads
        float2 f[8];
        #pragma unroll
        for (int u = 0; u < 8; ++u) f[u] = __half22float2(T[(size_t)s[u] * 48 + fl]);
        #pragma unroll
        for (int u = 0; u < 8; ++u) {
            accx = fmaf(ws[u], f[u].x, accx);
            accy = fmaf(ws[u], f[u].y, accy);
        }
    }
    for (; idx < end; ++idx) {
        int s = csr_src[idx];
        float w = dinv[s];
        float2 f = __half22float2(T[(size_t)s * 48 + fl]);
        accx = fmaf(w, f.x, accx);
        accy = fmaf(w, f.y, accy);
    }
    if (lane < 48) {
        float2 b = reinterpret_cast<const float2*>(bias)[lane];
        float ox = fmaxf(fmaf(dn, accx, b.x), 0.f);
        float oy = fmaxf(fmaf(dn, accy, b.y), 0.f);
        H[(size_t)node * 48 + lane] = __floats2half2_rn(ox, oy);
    }
}

// ---------------------------------------------------------------------------
// Output GEMM: out[n x 40] = H[n x 96](fp16) @ W[96 x 40] + bias (fp32 acc).
// ---------------------------------------------------------------------------
__global__ __launch_bounds__(320) void gemm_out_kernel(
        const __half2* __restrict__ A, const float* __restrict__ W,
        const float* __restrict__ bias, float* __restrict__ C, int n) {
    __shared__ float Wlds[96 * 40];
    int tid = threadIdx.y * 10 + threadIdx.x;
    for (int i = tid; i < 96 * 10; i += 320)
        reinterpret_cast<float4*>(Wlds)[i] = reinterpret_cast<const float4*>(W)[i];
    __syncthreads();

    int j    = threadIdx.x * 4;
    int node = blockIdx.x * 32 + threadIdx.y;
    int nc   = min(node, n - 1);
    const __half2* Ah = A + (size_t)nc * 48;
    float4 acc = make_float4(0.f, 0.f, 0.f, 0.f);
    for (int k2 = 0; k2 < 48; k2 += 2) {          // k = 2*k2 .. 2*k2+3
        float2 a01 = __half22float2(Ah[k2]);
        float2 a23 = __half22float2(Ah[k2 + 1]);
        int k = 2 * k2;
        float4 w0 = *reinterpret_cast<const float4*>(Wlds + (k + 0) * 40 + j);
        float4 w1 = *reinterpret_cast<const float4*>(Wlds + (k + 1) * 40 + j);
        float4 w2 = *reinterpret_cast<const float4*>(Wlds + (k + 2) * 40 + j);
        float4 w3 = *reinterpret_cast<const float4*>(Wlds + (k + 3) * 40 + j);
        acc.x += a01.x * w0.x + a01.y * w1.x + a23.x * w2.x + a23.y * w3.x;
        acc.y += a01.x * w0.y + a01.y * w1.y + a23.x * w2.y + a23.y * w3.y;
        acc.z += a01.x * w0.z + a01.y * w1.z + a23.x * w2.z + a23.y * w3.z;
        acc.w += a01.x * w0.w + a01.y * w1.w + a23.x * w2.w + a23.y * w3.w;
    }
    if (node < n) {
        float4 b = *reinterpret_cast<const float4*>(bias + j);
        acc.x += b.x; acc.y += b.y; acc.z += b.z; acc.w += b.w;
        *reinterpret_cast<float4*>(C + (size_t)node * 40 + j) = acc;
    }
}

// ---------------------------------------------------------------------------

extern "C" void kernel_launch(void* const* d_in, const int* in_sizes, int n_in,
                              void* d_out, int out_size, void* d_ws, size_t ws_size,
                              hipStream_t stream) {
    const float* x    = (const float*)d_in[0];
    const int*   ei   = (const int*)d_in[1];
    const float* W1   = (const float*)d_in[2];
    const float* b1   = (const float*)d_in[3];
    const float* W2   = (const float*)d_in[4];
    const float* b2   = (const float*)d_in[5];
    const float* Wout = (const float*)d_in[6];
    const float* bout = (const float*)d_in[7];
    float*       out  = (float*)d_out;

    const int* src = ei;            // edge_index[0]
    const int* dst = ei + N_EDGES;  // edge_index[1]

    char* ws = (char*)d_ws;
    size_t off = 0;
    auto alloc = [&](size_t bytes) {
        size_t o = off;
        off = (off + bytes + 511) & ~(size_t)511;
        return (void*)(ws + o);
    };
    int*     counts4   = (int*)    alloc((size_t)N_NODES * 4 * sizeof(int));
    int4*    cursor4   = (int4*)   alloc((size_t)N_NODES * sizeof(int4));
    int*     row_start = (int*)    alloc((N_NODES + 1) * sizeof(int));
    float*   dinv      = (float*)  alloc(N_NODES * sizeof(float));
    int*     blk_sums  = (int*)    alloc(64 * sizeof(int));
    int*     csr_src   = (int*)    alloc((size_t)N_EDGES * sizeof(int));
    __half*  BT1       = (__half*) alloc((size_t)96 * 136 * sizeof(__half));
    __half*  BT2       = (__half*) alloc((size_t)96 * 136 * sizeof(__half));
    __half2* Th        = (__half2*)alloc((size_t)N_NODES * 48 * sizeof(__half2));
    __half2* Hh        = (__half2*)alloc((size_t)N_NODES * 48 * sizeof(__half2));

    const int NSCAN = (N_NODES + 1023) / 1024;   // 49
    const int CB2   = (N_EDGES + 511) / 512;     // 1563 count blocks (2 edges/thr)
    const int FB4   = (N_EDGES + 1023) / 1024;   // 782 fill blocks (4 edges/thr)
    const int GB    = (N_NODES + 63) / 64;       // 782 gemm blocks

    // --- prep ---
    hipMemsetAsync(counts4, 0, (size_t)N_NODES * 4 * sizeof(int), stream);
    wt_kernel<<<(96 * 128 + 96 * 96 + 255) / 256, 256, 0, stream>>>(W1, W2, BT1, BT2);

    // --- fused: edge counting (no-return atomics) + layer-1 GEMM ---
    count_gemm1_kernel<<<CB2 + GB, 256, 0, stream>>>(
        dst, counts4, N_EDGES, x, BT1, (float4*)Th, N_NODES, CB2);

    // --- scan (2 launches) + fill (returning atomics, 4-deep ILP) ---
    scan_local_kernel<<<NSCAN, 1024, 0, stream>>>(
        (const int4*)counts4, row_start, dinv, blk_sums, N_NODES);
    scan_apply_kernel<<<NSCAN, 1024, 0, stream>>>(
        row_start, blk_sums, (const int4*)counts4, cursor4, N_NODES, NSCAN);
    fill_csr_kernel<<<FB4, 256, 0, stream>>>(
        src, dst, (int*)cursor4, csr_src, N_EDGES);

    // --- layer 1 aggregation -> H (fp16) ---
    agg_kernel<<<(N_NODES + 3) / 4, 256, 0, stream>>>(
        Th, row_start, csr_src, dinv, b1, Hh, N_NODES);

    // --- layer 2: GEMM (fp16 in) + aggregation ---
    mfma_gemm_kernel<F_HID, __half><<<GB, 256, 0, stream>>>(
        (const __half*)Hh, BT2, (float4*)Th, N_NODES);
    agg_kernel<<<(N_NODES + 3) / 4, 256, 0, stream>>>(
        Th, row_start, csr_src, dinv, b2, Hh, N_NODES);

    // --- output ---
    gemm_out_kernel<<<(N_NODES + 31) / 32, dim3(10, 32), 0, stream>>>(
        Hh, Wout, bout, out, N_NODES);
}

// Round 6
// 228.556 us; speedup vs baseline: 1.1182x; 1.1182x over previous
//
#include <hip/hip_runtime.h>
#include <hip/hip_fp16.h>

#define N_NODES 50000
#define N_EDGES 800000
#define F_INN   128
#define F_HID   96
#define F_OUTT  40

typedef _Float16 half8 __attribute__((ext_vector_type(8)));
typedef float    floatx4 __attribute__((ext_vector_type(4)));

// ---------------------------------------------------------------------------
// MFMA GEMM body: T[n][96] (fp16, UNSCALED) = X[n x FI] @ W, via 16x16x32 f16.
// A = W^T tile (m=feature), B = node rows (n=node). 4 waves x 16 nodes = 64/blk.
// TIN = float (load+cvt) or __half (direct half8 load).
// LDS: single 26112B buffer; BT tile while computing, then (after a barrier)
// reused as the 13312B OUT staging area -> 6 blocks/CU instead of 4.
// ---------------------------------------------------------------------------
template <int FI, typename TIN>
__device__ __forceinline__ void mfma_gemm_body(
        const TIN* __restrict__ X, const __half* __restrict__ BTg,
        float4* __restrict__ Th4, int n, int bx) {
    __shared__ __half BTl[96 * 136];          // 26112 B; reused as OUT staging
    __half* OUTl = BTl;                       // [4*16][104] after the barrier
    int tid = threadIdx.x;
    {   // stage BT (1632 x 16B)
        const int4* s = reinterpret_cast<const int4*>(BTg);
        int4* d = reinterpret_cast<int4*>(BTl);
        for (int i = tid; i < 96 * 136 / 8; i += 256) d[i] = s[i];
    }
    __syncthreads();

    int lane = tid & 63, w = tid >> 6;
    int lm = lane & 15, q = lane >> 4;
    int base = bx * 64 + w * 16;
    int node = base + lm;
    int nclamp = min(node, n - 1);
    const TIN* Xrow = X + (size_t)nclamp * FI;

    floatx4 cf[6];
    #pragma unroll
    for (int t = 0; t < 6; ++t) cf[t] = (floatx4){0.f, 0.f, 0.f, 0.f};

    constexpr int KS = FI / 32;
    #pragma unroll
    for (int ks = 0; ks < KS; ++ks) {
        // B-operand: lane holds k = 32*ks + q*8 .. +7 of this node's row
        half8 bv;
        if constexpr (sizeof(TIN) == 4) {
            const float4* xr = reinterpret_cast<const float4*>(Xrow + 32 * ks + q * 8);
            float4 f0 = xr[0], f1 = xr[1];
            union { half8 v; __half2 h[4]; } b;
            b.h[0] = __floats2half2_rn(f0.x, f0.y);
            b.h[1] = __floats2half2_rn(f0.z, f0.w);
            b.h[2] = __floats2half2_rn(f1.x, f1.y);
            b.h[3] = __floats2half2_rn(f1.z, f1.w);
            bv = b.v;
        } else {
            bv = *reinterpret_cast<const half8*>(Xrow + 32 * ks + q * 8);
        }
        #pragma unroll
        for (int t = 0; t < 6; ++t) {
            half8 a = *reinterpret_cast<const half8*>(
                &BTl[(t * 16 + lm) * 136 + q * 8 + 32 * ks]);
            cf[t] = __builtin_amdgcn_mfma_f32_16x16x32_f16(a, bv, cf[t], 0, 0, 0);
        }
    }

    __syncthreads();   // all waves done reading BTl; safe to reuse as OUTl

    // Epilogue: D[row=q*4+r][col=lm] = out[feature = t*16+q*4+r][node=lm].
    __half* orow = OUTl + (w * 16 + lm) * 104;
    #pragma unroll
    for (int t = 0; t < 6; ++t) {
        union { int2 i2; __half2 h[2]; } u;
        u.h[0] = __floats2half2_rn(cf[t][0], cf[t][1]);
        u.h[1] = __floats2half2_rn(cf[t][2], cf[t][3]);
        *reinterpret_cast<int2*>(&orow[t * 16 + q * 4]) = u.i2;
    }
    // Same-wave LDS round-trip: coalesced fp16 row store (12 x float4 per node).
    #pragma unroll
    for (int R = 0; R < 3; ++R) {
        int nl = lane >> 2, c = (lane & 3) + 4 * R;
        float4 v = *reinterpret_cast<const float4*>(&OUTl[(w * 16 + nl) * 104 + c * 8]);
        int gn = base + nl;
        if (gn < n) Th4[(size_t)gn * 12 + c] = v;
    }
}

// ---------------------------------------------------------------------------
// Fused: count (blocks [0,nCB)) + gemm L1 (blocks [nCB, nCB+GB)) — independent.
// Count phase: 2 edges/thread, XCD-SHARDED counters: shard = count-block & 7.
// Under round-robin block->XCD dispatch all atomics to shard s come from one
// XCD -> counter lines have a single writer class (no cross-XCD line
// ping-pong).  Shard arrays are 200KB apart (no false sharing).
// ---------------------------------------------------------------------------
__global__ __launch_bounds__(256) void count_gemm1_kernel(
        const int* __restrict__ dst, int* __restrict__ counts8, int* __restrict__ rank,
        int e, const float* __restrict__ X, const __half* __restrict__ BT1,
        float4* __restrict__ Th4, int n, int nCB) {
    if ((int)blockIdx.x < nCB) {
        int sh = blockIdx.x & 7;                 // block-uniform shard (SGPR)
        int* cnt = counts8 + sh * N_NODES;
        int i = blockIdx.x * 512 + threadIdx.x;
        int j = i + 256;
        int di = 0, dj = 0, ri, rj;
        bool bi = i < e, bj = j < e;
        if (bi) di = dst[i];
        if (bj) dj = dst[j];
        if (bi) ri = atomicAdd(&cnt[di], 1);
        if (bj) rj = atomicAdd(&cnt[dj], 1);
        if (bi) rank[i] = ri;
        if (bj) rank[j] = rj;
    } else {
        mfma_gemm_body<F_INN, float>(X, BT1, Th4, n, blockIdx.x - nCB);
    }
}

template <int FI, typename TIN>
__global__ __launch_bounds__(256) void mfma_gemm_kernel(
        const TIN* __restrict__ X, const __half* __restrict__ BTg,
        float4* __restrict__ Th4, int n) {
    mfma_gemm_body<FI, TIN>(X, BTg, Th4, n, blockIdx.x);
}

// ---------------------------------------------------------------------------
// Weight transpose + fp16: W[K x 96] -> BT[96][136] (pad 8). W1 & W2 together.
// ---------------------------------------------------------------------------
__global__ void wt_kernel(const float* __restrict__ W1, const float* __restrict__ W2,
                          __half* __restrict__ BT1, __half* __restrict__ BT2) {
    int i = blockIdx.x * 256 + threadIdx.x;
    if (i < 96 * 128) {
        int j = i / 128, k = i - j * 128;
        BT1[j * 136 + k] = __float2half(W1[k * 96 + j]);
    } else if (i < 96 * 128 + 96 * 96) {
        int t = i - 96 * 128;
        int j = t / 96, k = t - j * 96;
        BT2[j * 136 + k] = __float2half(W2[k * 96 + j]);
    }
}

// ---------------------------------------------------------------------------
// Scan phase 1: per-block exclusive scan of node degrees (sum of 8 shards);
// dinv; block sums.
// ---------------------------------------------------------------------------
__global__ __launch_bounds__(1024) void scan_local_kernel(
        const int* __restrict__ counts8, int* __restrict__ row_start,
        float* __restrict__ dinv, int* __restrict__ blk_sums, int n) {
    __shared__ int wave_sums[16];
    int tid = threadIdx.x, lane = tid & 63, wid = tid >> 6;
    int i = blockIdx.x * 1024 + tid;
    int v = 0;
    if (i < n) {
        #pragma unroll
        for (int s = 0; s < 8; ++s) v += counts8[s * N_NODES + i];
    }
    int val = v;
    #pragma unroll
    for (int off = 1; off < 64; off <<= 1) {
        int u = __shfl_up(val, off, 64);
        if (lane >= off) val += u;
    }
    if (lane == 63) wave_sums[wid] = val;
    __syncthreads();
    if (wid == 0) {
        int w = (lane < 16) ? wave_sums[lane] : 0;
        #pragma unroll
        for (int off = 1; off < 16; off <<= 1) {
            int u = __shfl_up(w, off, 64);
            if (lane >= off) w += u;
        }
        if (lane < 16) wave_sums[lane] = w;
    }
    __syncthreads();
    int excl = ((wid == 0) ? 0 : wave_sums[wid - 1]) + (val - v);
    if (i < n) {
        row_start[i] = excl;                  // local; global offset in phase 2
        dinv[i] = rsqrtf((float)(v + 1));     // +1 self loop
    }
    if (tid == 0) blk_sums[blockIdx.x] = wave_sums[15];
}

// ---------------------------------------------------------------------------
// Scan phase 2+3 fused: every block redundantly scans the <=64 block sums,
// applies its own offset, emits per-(node,shard) bases base8. Block 0 writes
// the grand total.
// ---------------------------------------------------------------------------
__global__ __launch_bounds__(1024) void scan_apply_kernel(
        int* __restrict__ row_start, const int* __restrict__ blk_sums,
        const int* __restrict__ counts8, int* __restrict__ base8, int n, int nblk) {
    __shared__ int s_my, s_tot;
    int tid = threadIdx.x;
    if (tid < 64) {
        int v = (tid < nblk) ? blk_sums[tid] : 0;
        int val = v;
        #pragma unroll
        for (int off = 1; off < 64; off <<= 1) {
            int u = __shfl_up(val, off, 64);
            if (tid >= off) val += u;
        }
        if (tid == (int)blockIdx.x) s_my = val - v;   // exclusive prefix
        if (tid == 63) s_tot = val;                   // grand total == E
    }
    __syncthreads();
    int i = blockIdx.x * 1024 + tid;
    if (i < n) {
        int b = row_start[i] + s_my;
        row_start[i] = b;
        int run = b;
        #pragma unroll
        for (int s = 0; s < 8; ++s) {
            base8[s * N_NODES + i] = run;
            run += counts8[s * N_NODES + i];
        }
    }
    if (blockIdx.x == 0 && tid == 0) row_start[n] = s_tot;
}

// Atomic-free fill: shard of edge i is (i>>9)&7 (its count-block & 7).
// pos = base8[shard][dst] + rank.  One scattered 4B store.
__global__ void fill_csr_kernel(const int* __restrict__ src, const int* __restrict__ dst,
                                const int* __restrict__ rank, const int* __restrict__ base8,
                                int* __restrict__ csr_src, int e) {
    int i = blockIdx.x * blockDim.x + threadIdx.x;
    if (i >= e) return;
    int sh = (i >> 9) & 7;
    csr_src[base8[sh * N_NODES + dst[i]] + rank[i]] = src[i];
}

// ---------------------------------------------------------------------------
// Aggregation: one wave per node; T unscaled fp16; per-edge weight dinv[s] is
// a wave-uniform SCALAR load.  H[d] = relu(dinv[d]*(Σ dinv[s]T[s] + dinv[d]T[d]) + b)
// Output fp16.
// ---------------------------------------------------------------------------
__global__ __launch_bounds__(256) void agg_kernel(
        const __half2* __restrict__ T, const int* __restrict__ row_start,
        const int* __restrict__ csr_src, const float* __restrict__ dinv,
        const float* __restrict__ bias, __half2* __restrict__ H, int n) {
    int lane = threadIdx.x & 63;
    int node = __builtin_amdgcn_readfirstlane(blockIdx.x * 4 + (threadIdx.x >> 6));
    if (node >= n) return;
    int fl = min(lane, 47);                    // lanes 48..63 duplicate lane 47

    float dn = dinv[node];
    float2 self = __half22float2(T[(size_t)node * 48 + fl]);
    float accx = dn * self.x, accy = dn * self.y;   // dinv[d]*T[d]

    int idx = row_start[node];
    int end = row_start[node + 1];
    for (; idx + 8 <= end; idx += 8) {
        int s[8];
        #pragma unroll
        for (int u = 0; u < 8; ++u) s[u] = csr_src[idx + u];
        float ws[8];
        #pragma unroll
        for (int u = 0; u < 8; ++u) ws[u] = dinv[s[u]];          // scalar loads
        float2 f[8];
        #pragma unroll
        for (int u = 0; u < 8; ++u) f[u] = __half22float2(T[(size_t)s[u] * 48 + fl]);
        #pragma unroll
        for (int u = 0; u < 8; ++u) {
            accx = fmaf(ws[u], f[u].x, accx);
            accy = fmaf(ws[u], f[u].y, accy);
        }
    }
    for (; idx < end; ++idx) {
        int s = csr_src[idx];
        float w = dinv[s];
        float2 f = __half22float2(T[(size_t)s * 48 + fl]);
        accx = fmaf(w, f.x, accx);
        accy = fmaf(w, f.y, accy);
    }
    if (lane < 48) {
        float2 b = reinterpret_cast<const float2*>(bias)[lane];
        float ox = fmaxf(fmaf(dn, accx, b.x), 0.f);
        float oy = fmaxf(fmaf(dn, accy, b.y), 0.f);
        H[(size_t)node * 48 + lane] = __floats2half2_rn(ox, oy);
    }
}

// ---------------------------------------------------------------------------
// Output GEMM: out[n x 40] = H[n x 96](fp16) @ W[96 x 40] + bias (fp32 acc).
// ---------------------------------------------------------------------------
__global__ __launch_bounds__(320) void gemm_out_kernel(
        const __half2* __restrict__ A, const float* __restrict__ W,
        const float* __restrict__ bias, float* __restrict__ C, int n) {
    __shared__ float Wlds[96 * 40];
    int tid = threadIdx.y * 10 + threadIdx.x;
    for (int i = tid; i < 96 * 10; i += 320)
        reinterpret_cast<float4*>(Wlds)[i] = reinterpret_cast<const float4*>(W)[i];
    __syncthreads();

    int j    = threadIdx.x * 4;
    int node = blockIdx.x * 32 + threadIdx.y;
    int nc   = min(node, n - 1);
    const __half2* Ah = A + (size_t)nc * 48;
    float4 acc = make_float4(0.f, 0.f, 0.f, 0.f);
    for (int k2 = 0; k2 < 48; k2 += 2) {          // k = 2*k2 .. 2*k2+3
        float2 a01 = __half22float2(Ah[k2]);
        float2 a23 = __half22float2(Ah[k2 + 1]);
        int k = 2 * k2;
        float4 w0 = *reinterpret_cast<const float4*>(Wlds + (k + 0) * 40 + j);
        float4 w1 = *reinterpret_cast<const float4*>(Wlds + (k + 1) * 40 + j);
        float4 w2 = *reinterpret_cast<const float4*>(Wlds + (k + 2) * 40 + j);
        float4 w3 = *reinterpret_cast<const float4*>(Wlds + (k + 3) * 40 + j);
        acc.x += a01.x * w0.x + a01.y * w1.x + a23.x * w2.x + a23.y * w3.x;
        acc.y += a01.x * w0.y + a01.y * w1.y + a23.x * w2.y + a23.y * w3.y;
        acc.z += a01.x * w0.z + a01.y * w1.z + a23.x * w2.z + a23.y * w3.z;
        acc.w += a01.x * w0.w + a01.y * w1.w + a23.x * w2.w + a23.y * w3.w;
    }
    if (node < n) {
        float4 b = *reinterpret_cast<const float4*>(bias + j);
        acc.x += b.x; acc.y += b.y; acc.z += b.z; acc.w += b.w;
        *reinterpret_cast<float4*>(C + (size_t)node * 40 + j) = acc;
    }
}

// ---------------------------------------------------------------------------

extern "C" void kernel_launch(void* const* d_in, const int* in_sizes, int n_in,
                              void* d_out, int out_size, void* d_ws, size_t ws_size,
                              hipStream_t stream) {
    const float* x    = (const float*)d_in[0];
    const int*   ei   = (const int*)d_in[1];
    const float* W1   = (const float*)d_in[2];
    const float* b1   = (const float*)d_in[3];
    const float* W2   = (const float*)d_in[4];
    const float* b2   = (const float*)d_in[5];
    const float* Wout = (const float*)d_in[6];
    const float* bout = (const float*)d_in[7];
    float*       out  = (float*)d_out;

    const int* src = ei;            // edge_index[0]
    const int* dst = ei + N_EDGES;  // edge_index[1]

    char* ws = (char*)d_ws;
    size_t off = 0;
    auto alloc = [&](size_t bytes) {
        size_t o = off;
        off = (off + bytes + 511) & ~(size_t)511;
        return (void*)(ws + o);
    };
    int*     counts8   = (int*)    alloc((size_t)8 * N_NODES * sizeof(int));
    int*     base8     = (int*)    alloc((size_t)8 * N_NODES * sizeof(int));
    int*     row_start = (int*)    alloc((N_NODES + 1) * sizeof(int));
    float*   dinv      = (float*)  alloc(N_NODES * sizeof(float));
    int*     blk_sums  = (int*)    alloc(64 * sizeof(int));
    int*     rank      = (int*)    alloc((size_t)N_EDGES * sizeof(int));
    int*     csr_src   = (int*)    alloc((size_t)N_EDGES * sizeof(int));
    __half*  BT1       = (__half*) alloc((size_t)96 * 136 * sizeof(__half));
    __half*  BT2       = (__half*) alloc((size_t)96 * 136 * sizeof(__half));
    __half2* Th        = (__half2*)alloc((size_t)N_NODES * 48 * sizeof(__half2));
    __half2* Hh        = (__half2*)alloc((size_t)N_NODES * 48 * sizeof(__half2));

    const int NSCAN = (N_NODES + 1023) / 1024;   // 49
    const int CB2   = (N_EDGES + 511) / 512;     // 1563 count blocks (2 edges/thr)
    const int FB    = (N_EDGES + 255) / 256;     // 3125 fill blocks
    const int GB    = (N_NODES + 63) / 64;       // 782 gemm blocks

    // --- prep ---
    hipMemsetAsync(counts8, 0, (size_t)8 * N_NODES * sizeof(int), stream);
    wt_kernel<<<(96 * 128 + 96 * 96 + 255) / 256, 256, 0, stream>>>(W1, W2, BT1, BT2);

    // --- fused: edge counting (XCD-sharded) + layer-1 GEMM ---
    count_gemm1_kernel<<<CB2 + GB, 256, 0, stream>>>(
        dst, counts8, rank, N_EDGES, x, BT1, (float4*)Th, N_NODES, CB2);

    // --- scan (2 launches) + fill ---
    scan_local_kernel<<<NSCAN, 1024, 0, stream>>>(
        counts8, row_start, dinv, blk_sums, N_NODES);
    scan_apply_kernel<<<NSCAN, 1024, 0, stream>>>(
        row_start, blk_sums, counts8, base8, N_NODES, NSCAN);
    fill_csr_kernel<<<FB, 256, 0, stream>>>(
        src, dst, rank, base8, csr_src, N_EDGES);

    // --- layer 1 aggregation -> H (fp16) ---
    agg_kernel<<<(N_NODES + 3) / 4, 256, 0, stream>>>(
        Th, row_start, csr_src, dinv, b1, Hh, N_NODES);

    // --- layer 2: GEMM (fp16 in) + aggregation ---
    mfma_gemm_kernel<F_HID, __half><<<GB, 256, 0, stream>>>(
        (const __half*)Hh, BT2, (float4*)Th, N_NODES);
    agg_kernel<<<(N_NODES + 3) / 4, 256, 0, stream>>>(
        Th, row_start, csr_src, dinv, b2, Hh, N_NODES);

    // --- output ---
    gemm_out_kernel<<<(N_NODES + 31) / 32, dim3(10, 32), 0, stream>>>(
        Hh, Wout, bout, out, N_NODES);
}